// Round 2
// baseline (164.714 us; speedup 1.0000x reference)
//
#include <hip/hip_runtime.h>
#include <math.h>

// EfficientGCN preprocess:
//   x: (N=128, C=3, T=300, V=25, M=2) fp32
//   out: (N, 3, 2C=6, T, V, M) fp32
// Branch 0 (joint):   [x ; x - x[:, :, :, 1, :]]
// Branch 1 (velocity):[x[t+1]-x[t] ; x[t+2]-x[t]] for t<T-2 else 0
// Branch 2 (bone):    bv = x - x[parent]; [bv ; acos(bv / (||bv||+1e-4))]
//
// One thread per 16B float4 = two consecutive (t,v) sites (both m).
// All 18 output stores are 16B nontemporal dwordx4 (clang ext_vector_type --
// HIP's float4 struct is rejected by __builtin_nontemporal_store).
// xv and x(t+2) loads are 16B too (rv0 even => +50-float offset stays aligned).

#define NN 128
#define CC 3
#define TT 300
#define VV 25
#define MM 2

typedef float f32x4 __attribute__((ext_vector_type(4)));
typedef float f32x2 __attribute__((ext_vector_type(2)));

constexpr int TVM  = TT * VV * MM;   // 15000 floats per (n,c) plane
constexpr int TV   = TT * VV;        // 7500 float2 per (n,c) plane
constexpr int Q    = TV / 2;         // 3750 float4 per (n,c) plane
constexpr int OUTP = 3 * 6 * TVM;    // floats per n in output

__global__ __launch_bounds__(256)
void egcn_pre_kernel(const float* __restrict__ x,
                     const int* __restrict__ conn,
                     float* __restrict__ out) {
    int j = blockIdx.x * blockDim.x + threadIdx.x;   // one thread per float4 (2 sites)
    if (j >= NN * Q) return;

    int n   = j / Q;
    int k   = j - n * Q;         // float4 index within a (n,c) plane
    int rv0 = 2 * k;             // float2 (t*V+v) index of site A
    int rv1 = rv0 + 1;           // site B
    int t0 = rv0 / VV, v0 = rv0 - t0 * VV;
    int t1 = rv1 / VV, v1 = rv1 - t1 * VV;

    int pa = conn[v0];
    int pb = conn[v1];
    bool hva = (t0 < TT - 2);
    bool hvb = (t1 < TT - 2);
    bool ld2 = (rv0 + 51 < TV);  // full float4 at +2 frames stays in-plane

    const float* xn = x + (size_t)n * CC * TVM;

    f32x4 xv[3], x2[3];
    f32x2 x1a[3], x1b[3], xca[3], xcb[3], xpa[3], xpb[3];
    #pragma unroll
    for (int c = 0; c < 3; ++c) {
        const float*  pc = xn + c * TVM;
        const f32x2* p2 = reinterpret_cast<const f32x2*>(pc);
        const f32x4* p4 = reinterpret_cast<const f32x4*>(pc);
        xv[c]  = p4[k];                                   // sites A,B (16B)
        x2[c]  = ld2 ? p4[k + VV] : (f32x4)(0.f);         // t+2 pair (16B)
        x1a[c] = hva ? p2[rv0 + VV] : (f32x2)(0.f);       // t+1
        x1b[c] = hvb ? p2[rv1 + VV] : (f32x2)(0.f);
        xca[c] = p2[t0 * VV + 1];                         // center joint
        xcb[c] = p2[t1 * VV + 1];
        xpa[c] = p2[t0 * VV + pa];                        // parent joint
        xpb[c] = p2[t1 * VV + pb];
    }

    // bone vectors + per-(site,m) inverse length
    f32x2 bva[3], bvb[3];
    float sa0 = 0.f, sa1 = 0.f, sb0 = 0.f, sb1 = 0.f;
    #pragma unroll
    for (int c = 0; c < 3; ++c) {
        bva[c].x = xv[c].x - xpa[c].x;
        bva[c].y = xv[c].y - xpa[c].y;
        bvb[c].x = xv[c].z - xpb[c].x;
        bvb[c].y = xv[c].w - xpb[c].y;
        sa0 += bva[c].x * bva[c].x;  sa1 += bva[c].y * bva[c].y;
        sb0 += bvb[c].x * bvb[c].x;  sb1 += bvb[c].y * bvb[c].y;
    }
    float ia0 = 1.0f / (sqrtf(sa0) + 1e-4f);
    float ia1 = 1.0f / (sqrtf(sa1) + 1e-4f);
    float ib0 = 1.0f / (sqrtf(sb0) + 1e-4f);
    float ib1 = 1.0f / (sqrtf(sb1) + 1e-4f);

    f32x4* o4 = reinterpret_cast<f32x4*>(out + (size_t)n * OUTP);
    #pragma unroll
    for (int c = 0; c < 3; ++c) {
        // branch 0: joint = [x ; x - center]
        __builtin_nontemporal_store(xv[c], &o4[(0 * 6 + c) * Q + k]);
        f32x4 rel;
        rel.x = xv[c].x - xca[c].x;  rel.y = xv[c].y - xca[c].y;
        rel.z = xv[c].z - xcb[c].x;  rel.w = xv[c].w - xcb[c].y;
        __builtin_nontemporal_store(rel, &o4[(0 * 6 + c + 3) * Q + k]);

        // branch 1: velocity = [x(t+1)-x(t) ; x(t+2)-x(t)], zero for t >= T-2
        f32x4 u1, u2;
        u1.x = hva ? x1a[c].x - xv[c].x : 0.f;
        u1.y = hva ? x1a[c].y - xv[c].y : 0.f;
        u1.z = hvb ? x1b[c].x - xv[c].z : 0.f;
        u1.w = hvb ? x1b[c].y - xv[c].w : 0.f;
        u2.x = hva ? x2[c].x - xv[c].x : 0.f;
        u2.y = hva ? x2[c].y - xv[c].y : 0.f;
        u2.z = hvb ? x2[c].z - xv[c].z : 0.f;
        u2.w = hvb ? x2[c].w - xv[c].w : 0.f;
        __builtin_nontemporal_store(u1, &o4[(1 * 6 + c) * Q + k]);
        __builtin_nontemporal_store(u2, &o4[(1 * 6 + c + 3) * Q + k]);

        // branch 2: bone = [bv ; acos(bv * inv_len)]
        f32x4 bn, ang;
        bn.x = bva[c].x;  bn.y = bva[c].y;  bn.z = bvb[c].x;  bn.w = bvb[c].y;
        __builtin_nontemporal_store(bn, &o4[(2 * 6 + c) * Q + k]);
        ang.x = acosf(bva[c].x * ia0);
        ang.y = acosf(bva[c].y * ia1);
        ang.z = acosf(bvb[c].x * ib0);
        ang.w = acosf(bvb[c].y * ib1);
        __builtin_nontemporal_store(ang, &o4[(2 * 6 + c + 3) * Q + k]);
    }
}

extern "C" void kernel_launch(void* const* d_in, const int* in_sizes, int n_in,
                              void* d_out, int out_size, void* d_ws, size_t ws_size,
                              hipStream_t stream) {
    const float* x   = (const float*)d_in[0];
    const int* conn  = (const int*)d_in[1];
    float* out       = (float*)d_out;

    int total = NN * Q;                   // 480,000 threads (2 sites each)
    int block = 256;
    int grid  = (total + block - 1) / block;   // 1875 blocks exactly
    egcn_pre_kernel<<<grid, block, 0, stream>>>(x, conn, out);
}